// Round 1
// baseline (1149.526 us; speedup 1.0000x reference)
//
#include <hip/hip_runtime.h>

// ---------------------------------------------------------------------------
// FusedExpertsNetwork: y = relu(x @ W1^T + b1) @ W2 + b2, per expert.
// E=8, C=4096, M=1024, H=4096, O=1024. Inputs fp32; compute bf16 MFMA.
//
// R2: 256x256 8-phase pipelined GEMM (m201 template, plain HIP):
//   T1 XCD-aware block swizzle, T2 XOR LDS swizzle (kept from R1, 0 conflicts),
//   T3+T4 8-phase schedule with counted s_waitcnt vmcnt(4) (never 0 in loop),
//   T5 s_setprio(1) around each 16-MFMA cluster.
// R1 (128^2, 2-barrier/K-step) was latency-bound at MfmaUtil 35% — the
// compiler's vmcnt(0) drain at every __syncthreads is structural. Here raw
// s_barrier + counted vmcnt keeps 2-3 staging units in flight across phases.
//
// Schedule (derived, hazard-checked): K-tile t, buffer b=t&1, phases:
//  p1 (kh0,mh0): read A[mi0-3]kh0 + B[ni0-3]kh0; stage A(t+1) rows{0-63,128-191}
//                -> b^1 (dead since p3 of t-1); MFMA; vmcnt(4); barrier
//  p2 (kh0,mh1): read A[mi4-7]kh0 (B reused in regs); stage B(t+1) rows128-255
//                -> b^1 (dead since p3 of t-1); MFMA; barrier
//  p3 (kh1,mh0): read A kh1 + B kh1; stage A(t+1) rows{64-127,192-255} -> b^1
//                (dead since p4 of t-1); MFMA; barrier
//  p4 (kh1,mh1): read A[mi4-7]kh1; stage B(t+2) rows0-127 -> b (B(b) dead
//                since p3 of t); MFMA; vmcnt(4); barrier
// Waits: vmcnt(4) = retain newest 2 stage-units (4 loads); retires everything
// phase-1/phase-2 of the NEXT k-tile reads. Margins >= 2.5 phases.
// ---------------------------------------------------------------------------

typedef __bf16 bf16x8 __attribute__((ext_vector_type(8)));
typedef float f32x4 __attribute__((ext_vector_type(4)));

__device__ __forceinline__ unsigned short f2bf(float f) {
  union { float f; unsigned int u; } v; v.f = f;
  unsigned int u = v.u;
  u += 0x7fffu + ((u >> 16) & 1u);   // round-to-nearest-even
  return (unsigned short)(u >> 16);
}

#define GLD_LDS16(gptr, lptr)                                               \
  __builtin_amdgcn_global_load_lds(                                         \
      (const __attribute__((address_space(1))) void*)(gptr),                \
      (__attribute__((address_space(3))) void*)(lptr), 16, 0, 0)

// --------------------------- fp32 -> bf16 copy ------------------------------
__global__ void cvt_bf16_kernel(const float* __restrict__ in,
                                unsigned short* __restrict__ out, long n) {
  long i = ((long)blockIdx.x * blockDim.x + threadIdx.x) * 4;
  if (i >= n) return;
  const float4 v = *(const float4*)(in + i);
  ushort4 o;
  o.x = f2bf(v.x); o.y = f2bf(v.y); o.z = f2bf(v.z); o.w = f2bf(v.w);
  *(ushort4*)(out + i) = o;
}

// ------------------- fp32 (H,O) -> bf16 (O,H) transpose ---------------------
__global__ void transpose_cvt_kernel(const float* __restrict__ in,
                                     unsigned short* __restrict__ out,
                                     int H, int O, long istride, long ostride) {
  __shared__ unsigned short tile[32][33];
  const float* inp = in + (long)blockIdx.z * istride;
  unsigned short* outp = out + (long)blockIdx.z * ostride;
  const int o0 = blockIdx.x * 32, h0 = blockIdx.y * 32;
  const int tx = threadIdx.x, ty = threadIdx.y;
#pragma unroll
  for (int r = ty; r < 32; r += 8)
    tile[r][tx] = f2bf(inp[(long)(h0 + r) * O + o0 + tx]);
  __syncthreads();
#pragma unroll
  for (int r = ty; r < 32; r += 8)
    outp[(long)(o0 + r) * H + h0 + tx] = tile[tx][r];
}

// --------------------------- bf16 gemm_bt -----------------------------------
// C[m,n] = sum_k A[m,k] * B[n,k]  (+ bias[n]); EPI=0: relu -> bf16 out
//                                              EPI=1: fp32 out
// Tile 256x256, BK=64, 512 threads (8 waves, 2x4), per-wave C = 128x64.
// LDS: element (row R, k) at R*BK + ((k/8) ^ (R&7))*8 + k%8  (R1's verified
// zero-conflict swizzle; staging pre-swizzles the GLOBAL k-chunk so the
// linear global_load_lds dest yields the swizzled layout).
#define BM 256
#define BN 256
#define BK 64

template <int EPI>
__global__ __launch_bounds__(512, 2) void gemm_bt_kernel(
    const unsigned short* __restrict__ A, const unsigned short* __restrict__ B,
    const float* __restrict__ bias, void* __restrict__ Cout,
    int Nd, int Kd, long sA, long sB, long sBias, long sC) {
  __shared__ unsigned short As[2][BM * BK];   // 64 KiB
  __shared__ unsigned short Bs[2][BN * BK];   // 64 KiB

  // ---- T1: XCD-aware tile swizzle (all grids have nwg % 8 == 0) ----
  const int nbx = gridDim.x;
  const int nbxy = nbx * gridDim.y;
  const int nwg = nbxy * gridDim.z;
  int gid = blockIdx.x + nbx * blockIdx.y + nbxy * blockIdx.z;
  gid = (gid & 7) * (nwg >> 3) + (gid >> 3);
  const int bz = gid / nbxy;
  const int rem = gid - bz * nbxy;
  const int by = rem / nbx;
  const int bx = rem - by * nbx;

  const unsigned short* Ae = A + (long)bz * sA;
  const unsigned short* Be = B + (long)bz * sB;
  const float* be = bias + (long)bz * sBias;

  const int tid = threadIdx.x;
  const int wave = tid >> 6;
  const int lane = tid & 63;
  const int wm = wave >> 2;   // wave row 0..1 (128 C-rows each)
  const int wn = wave & 3;    // wave col 0..3 (64 C-cols each)
  const int fr = lane & 15;   // frag row (m for A / n for B / col for D)
  const int quad = lane >> 4; // 0..3
  const int fsw = fr & 7;

  const int blockM = by * BM;
  const int blockN = bx * BN;

  // staging: one instr = 512 thr x 16B = 64 rows x 128B. tid covers row
  // band+tid/8, phys slot tid&7; global k-chunk pre-swizzled: (tid&7)^(row&7).
  const int srow = tid >> 3;                       // 0..63 within a band
  const int skc = ((tid & 7) ^ (srow & 7)) * 8;    // swizzled k elem offset
  const unsigned short* gA = Ae + (long)(blockM + srow) * Kd + skc;
  const unsigned short* gB = Be + (long)(blockN + srow) * Kd + skc;

  // LDS dest: wave-uniform base + lane*16 (HW); wave w covers rows band+w*8..+7
#define STAGE_A(buf, band, kt)                                              \
  GLD_LDS16(gA + (long)(band) * Kd + (kt) * BK,                             \
            &As[buf][(band) * BK + wave * 512])
#define STAGE_B(buf, band, kt)                                              \
  GLD_LDS16(gB + (long)(band) * Kd + (kt) * BK,                             \
            &Bs[buf][(band) * BK + wave * 512])
#define STAGE_A_MH0(buf, kt) { STAGE_A(buf, 0, kt);   STAGE_A(buf, 128, kt); }
#define STAGE_A_MH1(buf, kt) { STAGE_A(buf, 64, kt);  STAGE_A(buf, 192, kt); }
#define STAGE_B_R0(buf, kt)  { STAGE_B(buf, 0, kt);   STAGE_B(buf, 64, kt);  }
#define STAGE_B_R1(buf, kt)  { STAGE_B(buf, 128, kt); STAGE_B(buf, 192, kt); }
#define VMWAIT4 asm volatile("s_waitcnt vmcnt(4)" ::: "memory")

  f32x4 acc[8][4];
#pragma unroll
  for (int a = 0; a < 8; ++a)
#pragma unroll
    for (int b = 0; b < 4; ++b) acc[a][b] = (f32x4){0.f, 0.f, 0.f, 0.f};

  const int NT = Kd / BK;

  // loop-invariant read offsets
  const int aRow = (wm * 128 + fr) * BK;
  const int bRow = (wn * 64 + fr) * BK;
  const int s0 = (quad ^ fsw) * 8;         // kh=0 slot (chunks 0..3)
  const int s1 = ((4 + quad) ^ fsw) * 8;   // kh=1 slot (chunks 4..7)

  // ---- prologue: 5 stage-units (10 loads); retire first 3, keep 2 in flight
  STAGE_B_R0(0, 0);
  STAGE_A_MH0(0, 0);
  STAGE_B_R1(0, 0);
  STAGE_A_MH1(0, 0);
  STAGE_B_R0(1, (NT > 1 ? 1 : 0));
  VMWAIT4;
  __builtin_amdgcn_s_barrier();

  bf16x8 af[4], bfr[4];

  for (int t = 0; t < NT; ++t) {
    const int cur = t & 1;
    const int nxt = cur ^ 1;
    const int k1 = (t + 1 < NT) ? t + 1 : NT - 1;  // clamped: dead-region dummy
    const int k2 = (t + 2 < NT) ? t + 2 : NT - 1;
    const unsigned short* Asc = &As[cur][0];
    const unsigned short* Bsc = &Bs[cur][0];

    // ---------------- phase 1: kh=0, mh=0 ----------------
#pragma unroll
    for (int ni = 0; ni < 4; ++ni)
      bfr[ni] = *(const bf16x8*)&Bsc[bRow + ni * 16 * BK + s0];
#pragma unroll
    for (int i = 0; i < 4; ++i)
      af[i] = *(const bf16x8*)&Asc[aRow + i * 16 * BK + s0];
    STAGE_A_MH0(nxt, k1);
    __builtin_amdgcn_s_barrier();
    __builtin_amdgcn_s_setprio(1);
#pragma unroll
    for (int i = 0; i < 4; ++i)
#pragma unroll
      for (int ni = 0; ni < 4; ++ni)
        acc[i][ni] = __builtin_amdgcn_mfma_f32_16x16x32_bf16(
            af[i], bfr[ni], acc[i][ni], 0, 0, 0);
    __builtin_amdgcn_s_setprio(0);
    VMWAIT4;                       // W2: retires A(t)mh1 (needed by phase 2)
    __builtin_amdgcn_s_barrier();

    // ---------------- phase 2: kh=0, mh=1 ----------------
#pragma unroll
    for (int i = 0; i < 4; ++i)
      af[i] = *(const bf16x8*)&Asc[aRow + (64 + i * 16) * BK + s0];
    STAGE_B_R1(nxt, k1);
    __builtin_amdgcn_s_barrier();
    __builtin_amdgcn_s_setprio(1);
#pragma unroll
    for (int i = 0; i < 4; ++i)
#pragma unroll
      for (int ni = 0; ni < 4; ++ni)
        acc[4 + i][ni] = __builtin_amdgcn_mfma_f32_16x16x32_bf16(
            af[i], bfr[ni], acc[4 + i][ni], 0, 0, 0);
    __builtin_amdgcn_s_setprio(0);
    __builtin_amdgcn_s_barrier();

    // ---------------- phase 3: kh=1, mh=0 ----------------
#pragma unroll
    for (int ni = 0; ni < 4; ++ni)
      bfr[ni] = *(const bf16x8*)&Bsc[bRow + ni * 16 * BK + s1];
#pragma unroll
    for (int i = 0; i < 4; ++i)
      af[i] = *(const bf16x8*)&Asc[aRow + i * 16 * BK + s1];
    STAGE_A_MH1(nxt, k1);
    __builtin_amdgcn_s_barrier();
    __builtin_amdgcn_s_setprio(1);
#pragma unroll
    for (int i = 0; i < 4; ++i)
#pragma unroll
      for (int ni = 0; ni < 4; ++ni)
        acc[i][ni] = __builtin_amdgcn_mfma_f32_16x16x32_bf16(
            af[i], bfr[ni], acc[i][ni], 0, 0, 0);
    __builtin_amdgcn_s_setprio(0);
    __builtin_amdgcn_s_barrier();

    // ---------------- phase 4: kh=1, mh=1 ----------------
#pragma unroll
    for (int i = 0; i < 4; ++i)
      af[i] = *(const bf16x8*)&Asc[aRow + (64 + i * 16) * BK + s1];
    STAGE_B_R0(cur, k2);  // B(t+2) -> buffer (t+2)&1 == cur; B(cur) died at p3
    __builtin_amdgcn_s_barrier();
    __builtin_amdgcn_s_setprio(1);
#pragma unroll
    for (int i = 0; i < 4; ++i)
#pragma unroll
      for (int ni = 0; ni < 4; ++ni)
        acc[4 + i][ni] = __builtin_amdgcn_mfma_f32_16x16x32_bf16(
            af[i], bfr[ni], acc[4 + i][ni], 0, 0, 0);
    __builtin_amdgcn_s_setprio(0);
    VMWAIT4;                       // W1: retires everything next phase-1 reads
    __builtin_amdgcn_s_barrier();
  }

  // epilogue: D layout col = lane&15, row = quad*4 + reg  [m89-verified]
  float bv[4];
#pragma unroll
  for (int ni = 0; ni < 4; ++ni) bv[ni] = be[blockN + wn * 64 + ni * 16 + fr];

  if (EPI == 0) {
    unsigned short* Co = (unsigned short*)Cout + (long)bz * sC;
#pragma unroll
    for (int mi = 0; mi < 8; ++mi) {
      const int m = blockM + wm * 128 + mi * 16 + quad * 4;
#pragma unroll
      for (int r = 0; r < 4; ++r) {
        const long rowoff = (long)(m + r) * Nd;
#pragma unroll
        for (int ni = 0; ni < 4; ++ni) {
          float v = acc[mi][ni][r] + bv[ni];
          v = v > 0.f ? v : 0.f;
          Co[rowoff + blockN + wn * 64 + ni * 16 + fr] = f2bf(v);
        }
      }
    }
  } else {
    float* Co = (float*)Cout + (long)bz * sC;
#pragma unroll
    for (int mi = 0; mi < 8; ++mi) {
      const int m = blockM + wm * 128 + mi * 16 + quad * 4;
#pragma unroll
      for (int r = 0; r < 4; ++r) {
        const long rowoff = (long)(m + r) * Nd;
#pragma unroll
        for (int ni = 0; ni < 4; ++ni)
          Co[rowoff + blockN + wn * 64 + ni * 16 + fr] = acc[mi][ni][r] + bv[ni];
      }
    }
  }
}

// ---------------------------------------------------------------------------
extern "C" void kernel_launch(void* const* d_in, const int* in_sizes, int n_in,
                              void* d_out, int out_size, void* d_ws,
                              size_t ws_size, hipStream_t stream) {
  const float* x  = (const float*)d_in[0];
  const float* w1 = (const float*)d_in[1];
  const float* b1 = (const float*)d_in[2];
  const float* w2 = (const float*)d_in[3];
  const float* b2 = (const float*)d_in[4];
  float* out = (float*)d_out;

  const int E = 8, C = 4096, M = 1024, H = 4096, O = 1024;
  const long nx  = (long)C * M;
  const long nw1 = (long)H * M;
  const long nw2 = (long)O * H;
  const long nh  = (long)C * H;

  unsigned short* ws = (unsigned short*)d_ws;
  const size_t needBatch = (size_t)(E * (nx + nw1 + nw2 + nh)) * 2;  // 448 MiB

  if (ws_size >= needBatch) {
    unsigned short* xb  = ws;
    unsigned short* w1b = xb + E * nx;
    unsigned short* w2t = w1b + E * nw1;
    unsigned short* hb  = w2t + E * nw2;
    const long tx = E * nx, tw1 = E * nw1;
    cvt_bf16_kernel<<<tx / 1024, 256, 0, stream>>>(x, xb, tx);
    cvt_bf16_kernel<<<tw1 / 1024, 256, 0, stream>>>(w1, w1b, tw1);
    transpose_cvt_kernel<<<dim3(O / 32, H / 32, E), dim3(32, 8), 0, stream>>>(
        w2, w2t, H, O, (long)H * O, (long)O * H);
    gemm_bt_kernel<0><<<dim3(H / BN, C / BM, E), 512, 0, stream>>>(
        xb, w1b, b1, hb, H, M, nx, nw1, H, nh);
    gemm_bt_kernel<1><<<dim3(O / BN, C / BM, E), 512, 0, stream>>>(
        hb, w2t, b2, out, O, H, nh, nw2, O, (long)C * O);
  } else {
    unsigned short* xb  = ws;
    unsigned short* w1b = xb + nx;
    unsigned short* w2t = w1b + nw1;
    unsigned short* hb  = w2t + nw2;
    for (int e = 0; e < E; ++e) {
      cvt_bf16_kernel<<<nx / 1024, 256, 0, stream>>>(x + e * nx, xb, nx);
      cvt_bf16_kernel<<<nw1 / 1024, 256, 0, stream>>>(w1 + e * nw1, w1b, nw1);
      transpose_cvt_kernel<<<dim3(O / 32, H / 32, 1), dim3(32, 8), 0, stream>>>(
          w2 + e * nw2, w2t, H, O, 0, 0);
      gemm_bt_kernel<0><<<dim3(H / BN, C / BM, 1), 512, 0, stream>>>(
          xb, w1b, b1 + (long)e * H, hb, H, M, 0, 0, 0, 0);
      gemm_bt_kernel<1><<<dim3(O / BN, C / BM, 1), 512, 0, stream>>>(
          hb, w2t, b2 + (long)e * O, out + e * nx, O, H, 0, 0, 0, 0);
    }
  }
}

// Round 4
// 974.739 us; speedup vs baseline: 1.1793x; 1.1793x over previous
//
#include <hip/hip_runtime.h>

// ---------------------------------------------------------------------------
// FusedExpertsNetwork: y = relu(x @ W1^T + b1) @ W2 + b2, per expert.
// E=8, C=4096, M=1024, H=4096, O=1024. Inputs fp32; compute bf16 MFMA.
//
// R5 == R3/R4 resubmit. Both prior benches died at container acquire (no
// timing block => kernel never ran). Third full hazard audit found no hang
// mode: uniform barriers, drainable waits, vmcnt ledger closed, stripe/band
// stage slots strictly after last reader, WAR-safe across waves.
//
// Structure (m201 8-phase template):
//   - phase = one A-stripe (32 rows/wave) x FULL K=64: 16 MFMA (2mi x 4ni x 2kk)
//   - B(tile) read ONCE at p1/p5 into 8 bf16x8 regs, reused 4 phases
//     -> B LDS region dies after p1 -> early stage slots
//   - stage slots: p1:A1(V) p2:B0(W) p3:B1(W) p4:A0(W)
//                  p5:A1(W) p6:B0(X) p7:B1(X) p8:A0(X)   (W=U+2, X=V+2)
//   - vmcnt(6) ONLY at p4/p8: retires exactly the tile the next 4 phases
//     read; 3 half-tiles stay in flight (stage->read ~7 phases).
//   - barrier; lgkmcnt(0); setprio(1); MFMA x16; setprio(0); barrier
// ---------------------------------------------------------------------------

typedef __bf16 bf16x8 __attribute__((ext_vector_type(8)));
typedef float f32x4 __attribute__((ext_vector_type(4)));

__device__ __forceinline__ unsigned short f2bf(float f) {
  union { float f; unsigned int u; } v; v.f = f;
  unsigned int u = v.u;
  u += 0x7fffu + ((u >> 16) & 1u);   // round-to-nearest-even
  return (unsigned short)(u >> 16);
}

#define GLD_LDS16(gptr, lptr)                                               \
  __builtin_amdgcn_global_load_lds(                                         \
      (const __attribute__((address_space(1))) void*)(gptr),                \
      (__attribute__((address_space(3))) void*)(lptr), 16, 0, 0)

// --------------------------- fp32 -> bf16 copy ------------------------------
__global__ void cvt_bf16_kernel(const float* __restrict__ in,
                                unsigned short* __restrict__ out, long n) {
  long i = ((long)blockIdx.x * blockDim.x + threadIdx.x) * 4;
  if (i >= n) return;
  const float4 v = *(const float4*)(in + i);
  ushort4 o;
  o.x = f2bf(v.x); o.y = f2bf(v.y); o.z = f2bf(v.z); o.w = f2bf(v.w);
  *(ushort4*)(out + i) = o;
}

// ------------------- fp32 (H,O) -> bf16 (O,H) transpose ---------------------
__global__ void transpose_cvt_kernel(const float* __restrict__ in,
                                     unsigned short* __restrict__ out,
                                     int H, int O, long istride, long ostride) {
  __shared__ unsigned short tile[32][33];
  const float* inp = in + (long)blockIdx.z * istride;
  unsigned short* outp = out + (long)blockIdx.z * ostride;
  const int o0 = blockIdx.x * 32, h0 = blockIdx.y * 32;
  const int tx = threadIdx.x, ty = threadIdx.y;
#pragma unroll
  for (int r = ty; r < 32; r += 8)
    tile[r][tx] = f2bf(inp[(long)(h0 + r) * O + o0 + tx]);
  __syncthreads();
#pragma unroll
  for (int r = ty; r < 32; r += 8)
    outp[(long)(o0 + r) * H + h0 + tx] = tile[tx][r];
}

// --------------------------- bf16 gemm_bt -----------------------------------
// C[m,n] = sum_k A[m,k] * B[n,k]  (+ bias[n]); EPI=0: relu -> bf16 out
//                                              EPI=1: fp32 out
// Tile 256x256, BK=64, 512 threads (8 waves, 2x4), per-wave C = 128x64.
// LDS: element (row R, k) at R*BK + ((k/8) ^ (R&7))*8 + k%8  (zero-conflict
// swizzle; staging pre-swizzles the GLOBAL k-chunk so the linear
// global_load_lds dest yields the swizzled layout).
#define BM 256
#define BN 256
#define BK 64

template <int EPI>
__global__ __launch_bounds__(512, 2) void gemm_bt_kernel(
    const unsigned short* __restrict__ A, const unsigned short* __restrict__ B,
    const float* __restrict__ bias, void* __restrict__ Cout,
    int Nd, int Kd, long sA, long sB, long sBias, long sC) {
  __shared__ unsigned short As[2][BM * BK];   // 64 KiB
  __shared__ unsigned short Bs[2][BN * BK];   // 64 KiB

  // ---- T1: XCD-aware tile swizzle (all grids have nwg % 8 == 0) ----
  const int nbx = gridDim.x;
  const int nbxy = nbx * gridDim.y;
  const int nwg = nbxy * gridDim.z;
  int gid = blockIdx.x + nbx * blockIdx.y + nbxy * blockIdx.z;
  gid = (gid & 7) * (nwg >> 3) + (gid >> 3);
  const int bz = gid / nbxy;
  const int rem = gid - bz * nbxy;
  const int by = rem / nbx;
  const int bx = rem - by * nbx;

  const unsigned short* Ae = A + (long)bz * sA;
  const unsigned short* Be = B + (long)bz * sB;
  const float* be = bias + (long)bz * sBias;

  const int tid = threadIdx.x;
  const int wave = tid >> 6;
  const int lane = tid & 63;
  const int wm = wave >> 2;   // wave row 0..1 (128 C-rows each)
  const int wn = wave & 3;    // wave col 0..3 (64 C-cols each)
  const int fr = lane & 15;   // frag row (m for A / n for B / col for D)
  const int quad = lane >> 4; // 0..3
  const int fsw = fr & 7;

  const int blockM = by * BM;
  const int blockN = bx * BN;

  // staging: one instr = 512 thr x 16B = 64 rows x 128B. tid covers row
  // band+tid/8, phys slot tid&7; global k-chunk pre-swizzled: (tid&7)^(row&7).
  const int srow = tid >> 3;                       // 0..63 within a band
  const int skc = ((tid & 7) ^ (srow & 7)) * 8;    // swizzled k elem offset
  const unsigned short* gA = Ae + (long)(blockM + srow) * Kd + skc;
  const unsigned short* gB = Be + (long)(blockN + srow) * Kd + skc;

  // LDS dest: wave-uniform base + lane*16 (HW); wave w covers rows band+w*8..+7
#define STAGE_A(buf, band, kt)                                              \
  GLD_LDS16(gA + (long)(band) * Kd + (kt) * BK,                             \
            &As[buf][(band) * BK + wave * 512])
#define STAGE_B(buf, band, kt)                                              \
  GLD_LDS16(gB + (long)(band) * Kd + (kt) * BK,                             \
            &Bs[buf][(band) * BK + wave * 512])
#define STAGE_A_MH0(buf, kt) { STAGE_A(buf, 0, kt);   STAGE_A(buf, 128, kt); }
#define STAGE_A_MH1(buf, kt) { STAGE_A(buf, 64, kt);  STAGE_A(buf, 192, kt); }
#define STAGE_B_R0(buf, kt)  { STAGE_B(buf, 0, kt);   STAGE_B(buf, 64, kt);  }
#define STAGE_B_R1(buf, kt)  { STAGE_B(buf, 128, kt); STAGE_B(buf, 192, kt); }

#define BAR __builtin_amdgcn_s_barrier()
#define LGKM0 asm volatile("s_waitcnt lgkmcnt(0)" ::: "memory")
#define VMCNT6 asm volatile("s_waitcnt vmcnt(6)" ::: "memory")

  f32x4 acc[8][4];
#pragma unroll
  for (int a = 0; a < 8; ++a)
#pragma unroll
    for (int b = 0; b < 4; ++b) acc[a][b] = (f32x4){0.f, 0.f, 0.f, 0.f};

  const int NT = Kd / BK;   // even, >= 2 for all our shapes (16 and 64)

  // loop-invariant read offsets
  const int aBase = (wm * 128 + fr) * BK;
  const int bBase = (wn * 64 + fr) * BK;
  const int s0 = (quad ^ fsw) * 8;         // kk=0 slot (chunks 0..3)
  const int s1 = ((4 + quad) ^ fsw) * 8;   // kk=1 slot (chunks 4..7)

  // fragment regs: af[2*mi+kk] for current stripe; bw[2*ni+kk] held per tile
  bf16x8 af[4], bw[8];

#define READ_A(bf, s)                                                       \
  {                                                                         \
    const unsigned short* _p = &As[bf][aBase + (2 * (s)) * 16 * BK];        \
    af[0] = *(const bf16x8*)(_p + s0);                                      \
    af[1] = *(const bf16x8*)(_p + s1);                                      \
    af[2] = *(const bf16x8*)(_p + 16 * BK + s0);                            \
    af[3] = *(const bf16x8*)(_p + 16 * BK + s1);                            \
  }

#define READ_B(bf)                                                          \
  {                                                                         \
    _Pragma("unroll")                                                       \
    for (int ni = 0; ni < 4; ++ni) {                                        \
      bw[2 * ni]     = *(const bf16x8*)&Bs[bf][bBase + ni * 16 * BK + s0];  \
      bw[2 * ni + 1] = *(const bf16x8*)&Bs[bf][bBase + ni * 16 * BK + s1];  \
    }                                                                       \
  }

#define MFMA_STRIPE(s)                                                      \
  __builtin_amdgcn_s_setprio(1);                                            \
  _Pragma("unroll")                                                         \
  for (int mi = 0; mi < 2; ++mi)                                            \
    _Pragma("unroll")                                                       \
    for (int ni = 0; ni < 4; ++ni) {                                        \
      acc[2 * (s) + mi][ni] = __builtin_amdgcn_mfma_f32_16x16x32_bf16(      \
          af[2 * mi], bw[2 * ni], acc[2 * (s) + mi][ni], 0, 0, 0);          \
      acc[2 * (s) + mi][ni] = __builtin_amdgcn_mfma_f32_16x16x32_bf16(      \
          af[2 * mi + 1], bw[2 * ni + 1], acc[2 * (s) + mi][ni], 0, 0, 0);  \
    }                                                                       \
  __builtin_amdgcn_s_setprio(0);

  // ---- prologue: T0 fully (4 HT) + T1's B0,B1,A0 (3 HT); retire T0 ----
  STAGE_B_R0(0, 0);
  STAGE_B_R1(0, 0);
  STAGE_A_MH0(0, 0);
  STAGE_A_MH1(0, 0);
  STAGE_B_R0(1, 1);
  STAGE_B_R1(1, 1);
  STAGE_A_MH0(1, 1);
  VMCNT6;            // retire T0's 8 loads; keep T1's 3 half-tiles in flight
  BAR;

  for (int it = 0; it < NT / 2; ++it) {
    const int U = 2 * it;                        // buf0 tile
    const int kW = (U + 2 < NT) ? U + 2 : NT - 1;  // clamped: dead-region dummy
    const int kX = (U + 3 < NT) ? U + 3 : NT - 1;

    // ---- phase 1: tile U stripe 0 (+ all B(U)) ------ 12 ds_read_b128
    READ_B(0);
    READ_A(0, 0);
    STAGE_A_MH1(1, U + 1);     // A1(V): buf1 A1 dead since prev p8
    BAR; LGKM0;
    MFMA_STRIPE(0);
    BAR;

    // ---- phase 2: stripe 1 ----
    READ_A(0, 1);
    STAGE_B_R0(0, kW);         // buf0 B dead after p1
    BAR; LGKM0;
    MFMA_STRIPE(1);
    BAR;

    // ---- phase 3: stripe 2 ----
    READ_A(0, 2);
    STAGE_B_R1(0, kW);
    BAR; LGKM0;
    MFMA_STRIPE(2);
    BAR;

    // ---- phase 4: stripe 3 ----
    READ_A(0, 3);
    STAGE_A_MH0(0, kW);        // buf0 A stripes 0,1 dead after p2
    BAR; LGKM0;
    MFMA_STRIPE(3);
    VMCNT6;                    // retires B0,B1,A0,A1 of V; keeps W's 3 HT
    BAR;

    // ---- phase 5: tile V stripe 0 (+ all B(V)) ----
    READ_B(1);
    READ_A(1, 0);
    STAGE_A_MH1(0, kW);        // buf0 A stripes 2,3 dead after p4
    BAR; LGKM0;
    MFMA_STRIPE(0);
    BAR;

    // ---- phase 6: stripe 1 ----
    READ_A(1, 1);
    STAGE_B_R0(1, kX);         // buf1 B dead after p5
    BAR; LGKM0;
    MFMA_STRIPE(1);
    BAR;

    // ---- phase 7: stripe 2 ----
    READ_A(1, 2);
    STAGE_B_R1(1, kX);
    BAR; LGKM0;
    MFMA_STRIPE(2);
    BAR;

    // ---- phase 8: stripe 3 ----
    READ_A(1, 3);
    STAGE_A_MH0(1, kX);        // buf1 A stripes 0,1 dead after p6
    BAR; LGKM0;
    MFMA_STRIPE(3);
    VMCNT6;                    // retires all of W; keeps X's 3 HT
    BAR;
  }

  // epilogue: D layout col = lane&15, row = quad*4 + reg  [m89-verified]
  float bv[4];
#pragma unroll
  for (int ni = 0; ni < 4; ++ni) bv[ni] = be[blockN + wn * 64 + ni * 16 + fr];

  if (EPI == 0) {
    unsigned short* Co = (unsigned short*)Cout + (long)bz * sC;
#pragma unroll
    for (int mi = 0; mi < 8; ++mi) {
      const int m = blockM + wm * 128 + mi * 16 + quad * 4;
#pragma unroll
      for (int r = 0; r < 4; ++r) {
        const long rowoff = (long)(m + r) * Nd;
#pragma unroll
        for (int ni = 0; ni < 4; ++ni) {
          float v = acc[mi][ni][r] + bv[ni];
          v = v > 0.f ? v : 0.f;
          Co[rowoff + blockN + wn * 64 + ni * 16 + fr] = f2bf(v);
        }
      }
    }
  } else {
    float* Co = (float*)Cout + (long)bz * sC;
#pragma unroll
    for (int mi = 0; mi < 8; ++mi) {
      const int m = blockM + wm * 128 + mi * 16 + quad * 4;
#pragma unroll
      for (int r = 0; r < 4; ++r) {
        const long rowoff = (long)(m + r) * Nd;
#pragma unroll
        for (int ni = 0; ni < 4; ++ni)
          Co[rowoff + blockN + wn * 64 + ni * 16 + fr] = acc[mi][ni][r] + bv[ni];
      }
    }
  }
}

// ---------------------------------------------------------------------------
extern "C" void kernel_launch(void* const* d_in, const int* in_sizes, int n_in,
                              void* d_out, int out_size, void* d_ws,
                              size_t ws_size, hipStream_t stream) {
  const float* x  = (const float*)d_in[0];
  const float* w1 = (const float*)d_in[1];
  const float* b1 = (const float*)d_in[2];
  const float* w2 = (const float*)d_in[3];
  const float* b2 = (const float*)d_in[4];
  float* out = (float*)d_out;

  const int E = 8, C = 4096, M = 1024, H = 4096, O = 1024;
  const long nx  = (long)C * M;
  const long nw1 = (long)H * M;
  const long nw2 = (long)O * H;
  const long nh  = (long)C * H;

  unsigned short* ws = (unsigned short*)d_ws;
  const size_t needBatch = (size_t)(E * (nx + nw1 + nw2 + nh)) * 2;  // 448 MiB

  if (ws_size >= needBatch) {
    unsigned short* xb  = ws;
    unsigned short* w1b = xb + E * nx;
    unsigned short* w2t = w1b + E * nw1;
    unsigned short* hb  = w2t + E * nw2;
    const long tx = E * nx, tw1 = E * nw1;
    cvt_bf16_kernel<<<tx / 1024, 256, 0, stream>>>(x, xb, tx);
    cvt_bf16_kernel<<<tw1 / 1024, 256, 0, stream>>>(w1, w1b, tw1);
    transpose_cvt_kernel<<<dim3(O / 32, H / 32, E), dim3(32, 8), 0, stream>>>(
        w2, w2t, H, O, (long)H * O, (long)O * H);
    gemm_bt_kernel<0><<<dim3(H / BN, C / BM, E), 512, 0, stream>>>(
        xb, w1b, b1, hb, H, M, nx, nw1, H, nh);
    gemm_bt_kernel<1><<<dim3(O / BN, C / BM, E), 512, 0, stream>>>(
        hb, w2t, b2, out, O, H, nh, nw2, O, (long)C * O);
  } else {
    unsigned short* xb  = ws;
    unsigned short* w1b = xb + nx;
    unsigned short* w2t = w1b + nw1;
    unsigned short* hb  = w2t + nw2;
    for (int e = 0; e < E; ++e) {
      cvt_bf16_kernel<<<nx / 1024, 256, 0, stream>>>(x + e * nx, xb, nx);
      cvt_bf16_kernel<<<nw1 / 1024, 256, 0, stream>>>(w1 + e * nw1, w1b, nw1);
      transpose_cvt_kernel<<<dim3(O / 32, H / 32, 1), dim3(32, 8), 0, stream>>>(
          w2 + e * nw2, w2t, H, O, 0, 0);
      gemm_bt_kernel<0><<<dim3(H / BN, C / BM, 1), 512, 0, stream>>>(
          xb, w1b, b1 + (long)e * H, hb, H, M, 0, 0, 0, 0);
      gemm_bt_kernel<1><<<dim3(O / BN, C / BM, 1), 512, 0, stream>>>(
          hb, w2t, b2 + (long)e * O, out + e * nx, O, H, 0, 0, 0, 0);
    }
  }
}

// Round 5
// 898.728 us; speedup vs baseline: 1.2791x; 1.0846x over previous
//
#include <hip/hip_runtime.h>

// ---------------------------------------------------------------------------
// FusedExpertsNetwork: y = relu(x @ W1^T + b1) @ W2 + b2, per expert.
// E=8, C=4096, M=1024, H=4096, O=1024. Inputs fp32; compute bf16 MFMA.
//
// R5: 4-phase merged schedule. R4 (8-phase) measured 1520 cyc/phase against
// 621 cyc of MFMA => ~900 cyc/phase fixed overhead (2 barriers + lgkm drain +
// waits). Merge phases: phase = half wave-tile (64 rows) x full K=64
// = 32 MFMA (1242 cyc), ONE barrier per phase, no explicit lgkmcnt(0)
// (C-level ds_reads -> compiler emits fine-grained partial lgkm waits).
//
// Iter = 2 K-tiles (U=buf0, V=buf1), 4 phases:
//  P1: read B(U)+A_MH0(U); stage A_MH1(V);        MFMA half0; vmcnt(8); bar
//  P2: read A_MH1(U);      stage B(W)+A_MH0(W);   MFMA half1; vmcnt(8); bar
//  P3: read B(V)+A_MH0(V); stage A_MH1(W);        MFMA half0; vmcnt(8); bar
//  P4: read A_MH1(V);      stage B(X)+A_MH0(X);   MFMA half1; vmcnt(8); bar
//  (W=U+2->buf0, X=U+3->buf1; B held in regs across the K-tile's 2 phases)
// Ledger (verified, closes on itself): P1-start invariant = 8 outstanding
// [A1(U)2,B(V)4,A0(V)2]; each vmcnt(8) retires exactly what the next phase
// reads; stage->retire distance uniform 2.67 phases >> HBM latency.
// Region death: B+A_MH0 of a buf die after P1/P3 (B in regs after); A_MH1
// after P2/P4 -> every stage slot strictly follows its region's last reader.
// ---------------------------------------------------------------------------

typedef __bf16 bf16x8 __attribute__((ext_vector_type(8)));
typedef float f32x4 __attribute__((ext_vector_type(4)));

__device__ __forceinline__ unsigned short f2bf(float f) {
  union { float f; unsigned int u; } v; v.f = f;
  unsigned int u = v.u;
  u += 0x7fffu + ((u >> 16) & 1u);   // round-to-nearest-even
  return (unsigned short)(u >> 16);
}

#define GLD_LDS16(gptr, lptr)                                               \
  __builtin_amdgcn_global_load_lds(                                         \
      (const __attribute__((address_space(1))) void*)(gptr),                \
      (__attribute__((address_space(3))) void*)(lptr), 16, 0, 0)

// --------------------------- fp32 -> bf16 copy ------------------------------
__global__ void cvt_bf16_kernel(const float* __restrict__ in,
                                unsigned short* __restrict__ out, long n) {
  long i = ((long)blockIdx.x * blockDim.x + threadIdx.x) * 4;
  if (i >= n) return;
  const float4 v = *(const float4*)(in + i);
  ushort4 o;
  o.x = f2bf(v.x); o.y = f2bf(v.y); o.z = f2bf(v.z); o.w = f2bf(v.w);
  *(ushort4*)(out + i) = o;
}

// ------------------- fp32 (H,O) -> bf16 (O,H) transpose ---------------------
__global__ void transpose_cvt_kernel(const float* __restrict__ in,
                                     unsigned short* __restrict__ out,
                                     int H, int O, long istride, long ostride) {
  __shared__ unsigned short tile[32][33];
  const float* inp = in + (long)blockIdx.z * istride;
  unsigned short* outp = out + (long)blockIdx.z * ostride;
  const int o0 = blockIdx.x * 32, h0 = blockIdx.y * 32;
  const int tx = threadIdx.x, ty = threadIdx.y;
#pragma unroll
  for (int r = ty; r < 32; r += 8)
    tile[r][tx] = f2bf(inp[(long)(h0 + r) * O + o0 + tx]);
  __syncthreads();
#pragma unroll
  for (int r = ty; r < 32; r += 8)
    outp[(long)(o0 + r) * H + h0 + tx] = tile[tx][r];
}

// --------------------------- bf16 gemm_bt -----------------------------------
// C[m,n] = sum_k A[m,k] * B[n,k]  (+ bias[n]); EPI=0: relu -> bf16 out
//                                              EPI=1: fp32 out
// Tile 256x256, BK=64, 512 threads (8 waves, 2x4), per-wave C = 128x64.
// LDS: element (row R, k) at R*BK + ((k/8) ^ (R&7))*8 + k%8  (zero-conflict
// swizzle; staging pre-swizzles the GLOBAL k-chunk so the linear
// global_load_lds dest yields the swizzled layout).
#define BM 256
#define BN 256
#define BK 64

template <int EPI>
__global__ __launch_bounds__(512, 2) void gemm_bt_kernel(
    const unsigned short* __restrict__ A, const unsigned short* __restrict__ B,
    const float* __restrict__ bias, void* __restrict__ Cout,
    int Nd, int Kd, long sA, long sB, long sBias, long sC) {
  __shared__ unsigned short As[2][BM * BK];   // 64 KiB
  __shared__ unsigned short Bs[2][BN * BK];   // 64 KiB

  // ---- T1: XCD-aware tile swizzle (all grids have nwg % 8 == 0) ----
  const int nbx = gridDim.x;
  const int nbxy = nbx * gridDim.y;
  const int nwg = nbxy * gridDim.z;
  int gid = blockIdx.x + nbx * blockIdx.y + nbxy * blockIdx.z;
  gid = (gid & 7) * (nwg >> 3) + (gid >> 3);
  const int bz = gid / nbxy;
  const int rem = gid - bz * nbxy;
  const int by = rem / nbx;
  const int bx = rem - by * nbx;

  const unsigned short* Ae = A + (long)bz * sA;
  const unsigned short* Be = B + (long)bz * sB;
  const float* be = bias + (long)bz * sBias;

  const int tid = threadIdx.x;
  const int wave = tid >> 6;
  const int lane = tid & 63;
  const int wm = wave >> 2;   // wave row 0..1 (128 C-rows each)
  const int wn = wave & 3;    // wave col 0..3 (64 C-cols each)
  const int fr = lane & 15;   // frag row (m for A / n for B / col for D)
  const int quad = lane >> 4; // 0..3
  const int fsw = fr & 7;

  const int blockM = by * BM;
  const int blockN = bx * BN;

  // staging: one instr = 512 thr x 16B = 64 rows x 128B. tid covers row
  // band+tid/8, phys slot tid&7; global k-chunk pre-swizzled: (tid&7)^(row&7).
  const int srow = tid >> 3;                       // 0..63 within a band
  const int skc = ((tid & 7) ^ (srow & 7)) * 8;    // swizzled k elem offset
  const unsigned short* gA = Ae + (long)(blockM + srow) * Kd + skc;
  const unsigned short* gB = Be + (long)(blockN + srow) * Kd + skc;

  // LDS dest: wave-uniform base + lane*16 (HW); wave w covers rows band+w*8..+7
#define STAGE_A(buf, band, kt)                                              \
  GLD_LDS16(gA + (long)(band) * Kd + (kt) * BK,                             \
            &As[buf][(band) * BK + wave * 512])
#define STAGE_B(buf, band, kt)                                              \
  GLD_LDS16(gB + (long)(band) * Kd + (kt) * BK,                             \
            &Bs[buf][(band) * BK + wave * 512])
#define STAGE_A_MH0(buf, kt) { STAGE_A(buf, 0, kt);   STAGE_A(buf, 128, kt); }
#define STAGE_A_MH1(buf, kt) { STAGE_A(buf, 64, kt);  STAGE_A(buf, 192, kt); }
#define STAGE_B_ALL(buf, kt) { STAGE_B(buf, 0, kt);   STAGE_B(buf, 64, kt);  \
                               STAGE_B(buf, 128, kt); STAGE_B(buf, 192, kt); }

#define BAR __builtin_amdgcn_s_barrier()
#define VMCNT8 asm volatile("s_waitcnt vmcnt(8)" ::: "memory")

  f32x4 acc[8][4];
#pragma unroll
  for (int a = 0; a < 8; ++a)
#pragma unroll
    for (int b = 0; b < 4; ++b) acc[a][b] = (f32x4){0.f, 0.f, 0.f, 0.f};

  const int NT = Kd / BK;   // even, >= 4 for our shapes (16 and 64)

  // loop-invariant read offsets
  const int aBase = (wm * 128 + fr) * BK;
  const int bBase = (wn * 64 + fr) * BK;
  const int s0 = (quad ^ fsw) * 8;         // kk=0 slot (chunks 0..3)
  const int s1 = ((4 + quad) ^ fsw) * 8;   // kk=1 slot (chunks 4..7)

  // fragment regs: af[mi][kk] for current half; bw[ni][kk] held per K-tile
  bf16x8 af[4][2], bw[4][2];

#define READ_AH(bf, h)                                                      \
  {                                                                         \
    _Pragma("unroll")                                                       \
    for (int mi = 0; mi < 4; ++mi) {                                        \
      const unsigned short* _p =                                            \
          &As[bf][aBase + ((h) * 64 + mi * 16) * BK];                       \
      af[mi][0] = *(const bf16x8*)(_p + s0);                                \
      af[mi][1] = *(const bf16x8*)(_p + s1);                                \
    }                                                                       \
  }

#define READ_B(bf)                                                          \
  {                                                                         \
    _Pragma("unroll")                                                       \
    for (int ni = 0; ni < 4; ++ni) {                                        \
      const unsigned short* _p = &Bs[bf][bBase + ni * 16 * BK];             \
      bw[ni][0] = *(const bf16x8*)(_p + s0);                                \
      bw[ni][1] = *(const bf16x8*)(_p + s1);                                \
    }                                                                       \
  }

  // 32 MFMA; kk-outer => dependent reuse of each acc at distance 16
#define MFMA_HALF(h)                                                        \
  __builtin_amdgcn_s_setprio(1);                                            \
  _Pragma("unroll")                                                         \
  for (int kk = 0; kk < 2; ++kk)                                            \
    _Pragma("unroll")                                                       \
    for (int mi = 0; mi < 4; ++mi)                                          \
      _Pragma("unroll")                                                     \
      for (int ni = 0; ni < 4; ++ni)                                        \
        acc[(h) * 4 + mi][ni] = __builtin_amdgcn_mfma_f32_16x16x32_bf16(    \
            af[mi][kk], bw[ni][kk], acc[(h) * 4 + mi][ni], 0, 0, 0);        \
  __builtin_amdgcn_s_setprio(0);

  // ---- prologue: T0 (8 instr) + T1's B,A_MH0 (6 instr); retire T0's P1 deps
  STAGE_B_ALL(0, 0);
  STAGE_A_MH0(0, 0);
  STAGE_A_MH1(0, 0);
  STAGE_B_ALL(1, 1);
  STAGE_A_MH0(1, 1);
  VMCNT8;   // retires B(0)+A_MH0(0); keeps [A1(0)2,B(1)4,A0(1)2] = invariant
  BAR;

  for (int it = 0; it < NT / 2; ++it) {
    const int U = 2 * it;                          // buf0 tile
    const int kW = (U + 2 < NT) ? U + 2 : NT - 1;  // clamped: dead-region dummy
    const int kX = (U + 3 < NT) ? U + 3 : NT - 1;

    // ---- P1: tile U half 0 (+ all B(U)) ----
    READ_B(0);
    READ_AH(0, 0);
    STAGE_A_MH1(1, U + 1);     // buf1 A_MH1 dead since prev P4
    MFMA_HALF(0);
    VMCNT8;                    // retires A1(U): P2 reads it
    BAR;

    // ---- P2: tile U half 1 (B reused in regs) ----
    READ_AH(0, 1);
    STAGE_B_ALL(0, kW);        // buf0 B dead after P1
    STAGE_A_MH0(0, kW);        // buf0 A_MH0 dead after P1
    MFMA_HALF(1);
    VMCNT8;                    // retires B(V)+A0(V): P3 reads them
    BAR;

    // ---- P3: tile V half 0 (+ all B(V)) ----
    READ_B(1);
    READ_AH(1, 0);
    STAGE_A_MH1(0, kW);        // buf0 A_MH1 dead after P2
    MFMA_HALF(0);
    VMCNT8;                    // retires A1(V): P4 reads it
    BAR;

    // ---- P4: tile V half 1 ----
    READ_AH(1, 1);
    STAGE_B_ALL(1, kX);        // buf1 B dead after P3
    STAGE_A_MH0(1, kX);        // buf1 A_MH0 dead after P3
    MFMA_HALF(1);
    VMCNT8;                    // retires B(W)+A0(W): next P1 reads them
    BAR;
  }

  // epilogue: D layout col = lane&15, row = quad*4 + reg  [m89-verified]
  float bv[4];
#pragma unroll
  for (int ni = 0; ni < 4; ++ni) bv[ni] = be[blockN + wn * 64 + ni * 16 + fr];

  if (EPI == 0) {
    unsigned short* Co = (unsigned short*)Cout + (long)bz * sC;
#pragma unroll
    for (int mi = 0; mi < 8; ++mi) {
      const int m = blockM + wm * 128 + mi * 16 + quad * 4;
#pragma unroll
      for (int r = 0; r < 4; ++r) {
        const long rowoff = (long)(m + r) * Nd;
#pragma unroll
        for (int ni = 0; ni < 4; ++ni) {
          float v = acc[mi][ni][r] + bv[ni];
          v = v > 0.f ? v : 0.f;
          Co[rowoff + blockN + wn * 64 + ni * 16 + fr] = f2bf(v);
        }
      }
    }
  } else {
    float* Co = (float*)Cout + (long)bz * sC;
#pragma unroll
    for (int mi = 0; mi < 8; ++mi) {
      const int m = blockM + wm * 128 + mi * 16 + quad * 4;
#pragma unroll
      for (int r = 0; r < 4; ++r) {
        const long rowoff = (long)(m + r) * Nd;
#pragma unroll
        for (int ni = 0; ni < 4; ++ni)
          Co[rowoff + blockN + wn * 64 + ni * 16 + fr] = acc[mi][ni][r] + bv[ni];
      }
    }
  }
}

// ---------------------------------------------------------------------------
extern "C" void kernel_launch(void* const* d_in, const int* in_sizes, int n_in,
                              void* d_out, int out_size, void* d_ws,
                              size_t ws_size, hipStream_t stream) {
  const float* x  = (const float*)d_in[0];
  const float* w1 = (const float*)d_in[1];
  const float* b1 = (const float*)d_in[2];
  const float* w2 = (const float*)d_in[3];
  const float* b2 = (const float*)d_in[4];
  float* out = (float*)d_out;

  const int E = 8, C = 4096, M = 1024, H = 4096, O = 1024;
  const long nx  = (long)C * M;
  const long nw1 = (long)H * M;
  const long nw2 = (long)O * H;
  const long nh  = (long)C * H;

  unsigned short* ws = (unsigned short*)d_ws;
  const size_t needBatch = (size_t)(E * (nx + nw1 + nw2 + nh)) * 2;  // 448 MiB

  if (ws_size >= needBatch) {
    unsigned short* xb  = ws;
    unsigned short* w1b = xb + E * nx;
    unsigned short* w2t = w1b + E * nw1;
    unsigned short* hb  = w2t + E * nw2;
    const long tx = E * nx, tw1 = E * nw1;
    cvt_bf16_kernel<<<tx / 1024, 256, 0, stream>>>(x, xb, tx);
    cvt_bf16_kernel<<<tw1 / 1024, 256, 0, stream>>>(w1, w1b, tw1);
    transpose_cvt_kernel<<<dim3(O / 32, H / 32, E), dim3(32, 8), 0, stream>>>(
        w2, w2t, H, O, (long)H * O, (long)O * H);
    gemm_bt_kernel<0><<<dim3(H / BN, C / BM, E), 512, 0, stream>>>(
        xb, w1b, b1, hb, H, M, nx, nw1, H, nh);
    gemm_bt_kernel<1><<<dim3(O / BN, C / BM, E), 512, 0, stream>>>(
        hb, w2t, b2, out, O, H, nh, nw2, O, (long)C * O);
  } else {
    unsigned short* xb  = ws;
    unsigned short* w1b = xb + nx;
    unsigned short* w2t = w1b + nw1;
    unsigned short* hb  = w2t + nw2;
    for (int e = 0; e < E; ++e) {
      cvt_bf16_kernel<<<nx / 1024, 256, 0, stream>>>(x + e * nx, xb, nx);
      cvt_bf16_kernel<<<nw1 / 1024, 256, 0, stream>>>(w1 + e * nw1, w1b, nw1);
      transpose_cvt_kernel<<<dim3(O / 32, H / 32, 1), dim3(32, 8), 0, stream>>>(
          w2 + e * nw2, w2t, H, O, 0, 0);
      gemm_bt_kernel<0><<<dim3(H / BN, C / BM, 1), 512, 0, stream>>>(
          xb, w1b, b1 + (long)e * H, hb, H, M, 0, 0, 0, 0);
      gemm_bt_kernel<1><<<dim3(O / BN, C / BM, 1), 512, 0, stream>>>(
          hb, w2t, b2 + (long)e * O, out + e * nx, O, H, 0, 0, 0, 0);
    }
  }
}